// Round 1
// baseline (154.820 us; speedup 1.0000x reference)
//
#include <hip/hip_runtime.h>
#include <stdint.h>

// Problem constants
#define B_  1024
#define D_  512
#define K_  255
#define L_  256
#define C_  80

typedef __attribute__((ext_vector_type(8))) short bf16x8;
typedef __attribute__((ext_vector_type(4))) float f32x4;

// async global->LDS, 16B per lane. LDS dst is wave-uniform base + lane*16;
// our per-lane dst pointers are constructed to be exactly that.
#define GLD(gsrc, ldst) \
  __builtin_amdgcn_global_load_lds((const __attribute__((address_space(1))) void*)(gsrc), \
                                   (__attribute__((address_space(3))) void*)(ldst), 16, 0, 0)

// round-to-nearest-even fp32 -> bf16 (inputs are finite random normals; no NaN care)
__device__ __forceinline__ short cvt_bf16(float f) {
    unsigned u = __float_as_uint(f);
    u += 0x7FFFu + ((u >> 16) & 1u);
    return (short)(u >> 16);
}

typedef __attribute__((ext_vector_type(8))) short short8;

// ---------------------------------------------------------------------------
// Kernel 1: convert leaf_W (20480x512) and x (1024x512) fp32 -> bf16 in ws
// ---------------------------------------------------------------------------
__global__ void convert_kernel(const float* __restrict__ w, const float* __restrict__ x,
                               short* __restrict__ wb, short* __restrict__ xb) {
    size_t i0 = (size_t)blockIdx.x * blockDim.x + threadIdx.x;
    size_t stride = (size_t)gridDim.x * blockDim.x;
    // W: 10485760 elems = 1310720 groups of 8
    for (size_t v = i0; v < 1310720u; v += stride) {
        float4 a = ((const float4*)w)[v * 2];
        float4 b = ((const float4*)w)[v * 2 + 1];
        short8 o;
        o[0] = cvt_bf16(a.x); o[1] = cvt_bf16(a.y); o[2] = cvt_bf16(a.z); o[3] = cvt_bf16(a.w);
        o[4] = cvt_bf16(b.x); o[5] = cvt_bf16(b.y); o[6] = cvt_bf16(b.z); o[7] = cvt_bf16(b.w);
        ((short8*)wb)[v] = o;
    }
    // x: 524288 elems = 65536 groups of 8
    for (size_t v = i0; v < 65536u; v += stride) {
        float4 a = ((const float4*)x)[v * 2];
        float4 b = ((const float4*)x)[v * 2 + 1];
        short8 o;
        o[0] = cvt_bf16(a.x); o[1] = cvt_bf16(a.y); o[2] = cvt_bf16(a.z); o[3] = cvt_bf16(a.w);
        o[4] = cvt_bf16(b.x); o[5] = cvt_bf16(b.y); o[6] = cvt_bf16(b.z); o[7] = cvt_bf16(b.w);
        ((short8*)xb)[v] = o;
    }
}

// ---------------------------------------------------------------------------
// Kernel 2: node_sim (fp32, exact) + leaf probabilities.
// One block handles 4 batch rows. Thread t = node k (t<255); x rows in LDS,
// broadcast float4 reads; ne row read per-thread (L2-resident, 0.5 MB).
// Then thread t = leaf t traverses the 8-level path per batch row.
// ---------------------------------------------------------------------------
__global__ __launch_bounds__(256) void node_kernel(const float* __restrict__ x,
                                                   const float* __restrict__ ne,
                                                   float* __restrict__ out1,
                                                   float* __restrict__ p_ws) {
    __shared__ __align__(16) float xs[4 * D_];   // 8 KB
    __shared__ float ss[4 * K_];                 // sigmoids per row
    const int t = threadIdx.x;
    const int b0 = blockIdx.x * 4;

    // load 4 x rows (2048 floats = 512 float4)
    const float4* xg = (const float4*)(x + (size_t)b0 * D_);
    ((float4*)xs)[t]       = xg[t];
    ((float4*)xs)[t + 256] = xg[t + 256];
    __syncthreads();

    if (t < K_) {
        const float4* nr = (const float4*)(ne + (size_t)t * D_);
        float acc0 = 0.f, acc1 = 0.f, acc2 = 0.f, acc3 = 0.f, nrm = 0.f;
        #pragma unroll 4
        for (int d4 = 0; d4 < D_ / 4; ++d4) {
            float4 nv = nr[d4];
            nrm += nv.x * nv.x + nv.y * nv.y + nv.z * nv.z + nv.w * nv.w;
            float4 x0 = ((const float4*)xs)[d4];
            float4 x1 = ((const float4*)xs)[128 + d4];
            float4 x2 = ((const float4*)xs)[256 + d4];
            float4 x3 = ((const float4*)xs)[384 + d4];
            acc0 += nv.x * x0.x + nv.y * x0.y + nv.z * x0.z + nv.w * x0.w;
            acc1 += nv.x * x1.x + nv.y * x1.y + nv.z * x1.z + nv.w * x1.w;
            acc2 += nv.x * x2.x + nv.y * x2.y + nv.z * x2.z + nv.w * x2.w;
            acc3 += nv.x * x3.x + nv.y * x3.y + nv.z * x3.z + nv.w * x3.w;
        }
        float inv = rsqrtf(nrm);
        float a[4] = {acc0, acc1, acc2, acc3};
        #pragma unroll
        for (int b = 0; b < 4; ++b) {
            float sig = 1.f / (1.f + __expf(-a[b] * inv));
            ss[b * K_ + t] = sig;
            out1[(size_t)(b0 + b) * K_ + t] = sig;
        }
    }
    __syncthreads();

    // leaf probabilities: thread t = leaf index
    #pragma unroll
    for (int b = 0; b < 4; ++b) {
        float prob = 1.f;
        int node = 0;
        #pragma unroll
        for (int d = 0; d < 8; ++d) {
            int bit = (t >> (7 - d)) & 1;
            float s = ss[b * K_ + node];
            prob *= bit ? (1.f - s) : s;
            node = 2 * node + 1 + bit;
        }
        p_ws[(size_t)(b0 + b) * L_ + t] = prob;
    }
}

// ---------------------------------------------------------------------------
// Kernel 3: main fused GEMM.
//   partial[lc][b][c] = sum_{l in chunk} p[b,l] * (x[b]·W_{l,c} + bias_{l,c})
// M_tile=128, l_chunk=4, BK=64, 16x16x32 bf16 MFMA, fp32 epilogue.
// Grid = 8 m-tiles x 64 l-chunks = 512 blocks, 256 threads (4 waves).
// Wave tile = 32 rows x 80 cols (2 m-frags x 5 n-frags).
// LDS tiles stored as 16B granules with XOR-by-(row&7) swizzle: frag
// ds_read_b128 lands 2-way on banks (free), staging stays lane-contiguous.
// ---------------------------------------------------------------------------
__global__ __launch_bounds__(256, 2) void gemm_kernel(const short* __restrict__ xb,
                                                      const short* __restrict__ wb,
                                                      const float* __restrict__ p,
                                                      const float* __restrict__ lb,
                                                      float* __restrict__ partial) {
    __shared__ __align__(16) short Ald[1024 * 8];  // 128 rows x 8 granules x 8 bf16 = 16 KB
    __shared__ __align__(16) short Bld[640 * 8];   // 80 rows x 8 granules = 10 KB
    __shared__ float p_ld[128];
    __shared__ float b_ld[80];

    const int tid  = threadIdx.x;
    const int lane = tid & 63;
    const int wave = tid >> 6;
    const int q    = lane >> 4;
    const int r    = lane & 15;
    const int wrow = wave * 32;
    const int mt   = blockIdx.x & 7;
    const int lc   = blockIdx.x >> 3;

    f32x4 outacc[2][5];
    #pragma unroll
    for (int mf = 0; mf < 2; ++mf)
        #pragma unroll
        for (int nf = 0; nf < 5; ++nf)
            outacc[mf][nf] = (f32x4){0.f, 0.f, 0.f, 0.f};

    const bf16x8* Av = (const bf16x8*)Ald;
    const bf16x8* Bv = (const bf16x8*)Bld;

    for (int li = 0; li < 4; ++li) {
        const int l = lc * 4 + li;
        f32x4 dec[2][5];
        #pragma unroll
        for (int mf = 0; mf < 2; ++mf)
            #pragma unroll
            for (int nf = 0; nf < 5; ++nf)
                dec[mf][nf] = (f32x4){0.f, 0.f, 0.f, 0.f};

        for (int kb = 0; kb < 8; ++kb) {
            __syncthreads();  // previous compute done before overwriting tiles
            // stage A: 1024 granules, 4 per thread
            #pragma unroll
            for (int j = 0; j < 4; ++j) {
                int ph = j * 256 + tid;
                int rr = ph >> 3;
                int g  = (ph & 7) ^ (rr & 7);
                const short* src = xb + ((size_t)(mt * 128 + rr) * D_ + kb * 64 + g * 8);
                GLD(src, Ald + ph * 8);
            }
            // stage B: 640 granules (80 rows of W_l)
            #pragma unroll
            for (int j = 0; j < 2; ++j) {
                int ph = j * 256 + tid;
                int cc = ph >> 3;
                int g  = (ph & 7) ^ (cc & 7);
                const short* src = wb + ((size_t)(l * C_ + cc) * D_ + kb * 64 + g * 8);
                GLD(src, Bld + ph * 8);
            }
            if (tid < 128) {  // wave-uniform: waves 0,1 only
                int ph = 512 + tid;
                int cc = ph >> 3;
                int g  = (ph & 7) ^ (cc & 7);
                const short* src = wb + ((size_t)(l * C_ + cc) * D_ + kb * 64 + g * 8);
                GLD(src, Bld + ph * 8);
            }
            if (kb == 0) {
                if (tid < 128) p_ld[tid] = p[(size_t)(mt * 128 + tid) * L_ + l];
                if (tid < 80)  b_ld[tid] = lb[l * C_ + tid];
            }
            __syncthreads();  // drains vmcnt(0): global_load_lds complete

            #pragma unroll
            for (int ks = 0; ks < 2; ++ks) {
                const int g = ks * 4 + q;
                bf16x8 af[2], bfr[5];
                #pragma unroll
                for (int mf = 0; mf < 2; ++mf) {
                    int rl = wrow + mf * 16 + r;
                    af[mf] = Av[rl * 8 + (g ^ (rl & 7))];
                }
                #pragma unroll
                for (int nf = 0; nf < 5; ++nf) {
                    int cl = nf * 16 + r;
                    bfr[nf] = Bv[cl * 8 + (g ^ (cl & 7))];
                }
                #pragma unroll
                for (int mf = 0; mf < 2; ++mf)
                    #pragma unroll
                    for (int nf = 0; nf < 5; ++nf)
                        dec[mf][nf] = __builtin_amdgcn_mfma_f32_16x16x32_bf16(
                            af[mf], bfr[nf], dec[mf][nf], 0, 0, 0);
            }
        }

        // fp32 epilogue: out += p[row] * (dec + bias[col])
        #pragma unroll
        for (int mf = 0; mf < 2; ++mf) {
            #pragma unroll
            for (int nf = 0; nf < 5; ++nf) {
                float bv = b_ld[nf * 16 + r];
                #pragma unroll
                for (int i = 0; i < 4; ++i) {
                    int row = wrow + mf * 16 + q * 4 + i;
                    outacc[mf][nf][i] += p_ld[row] * (dec[mf][nf][i] + bv);
                }
            }
        }
    }

    // store partials: partial[lc][1024 rows][80 cols], this block owns 128 rows
    const size_t rbase = (size_t)lc * B_ + mt * 128;
    #pragma unroll
    for (int mf = 0; mf < 2; ++mf)
        #pragma unroll
        for (int nf = 0; nf < 5; ++nf)
            #pragma unroll
            for (int i = 0; i < 4; ++i) {
                int row = wrow + mf * 16 + q * 4 + i;
                int col = nf * 16 + r;
                partial[(rbase + row) * C_ + col] = outacc[mf][nf][i];
            }
}

// ---------------------------------------------------------------------------
// Kernel 4: reduce 64 l-chunk partials -> out0 (1024x80)
// ---------------------------------------------------------------------------
__global__ void reduce_kernel(const float* __restrict__ partial, float* __restrict__ out0) {
    int idx = blockIdx.x * 256 + threadIdx.x;  // < 81920
    float s = 0.f;
    #pragma unroll 8
    for (int j = 0; j < 64; ++j)
        s += partial[(size_t)j * (B_ * C_) + idx];
    out0[idx] = s;
}

// ---------------------------------------------------------------------------
extern "C" void kernel_launch(void* const* d_in, const int* in_sizes, int n_in,
                              void* d_out, int out_size, void* d_ws, size_t ws_size,
                              hipStream_t stream) {
    const float* x  = (const float*)d_in[0];  // 1024x512
    const float* ne = (const float*)d_in[1];  // 255x512
    const float* lW = (const float*)d_in[2];  // 20480x512
    const float* lb = (const float*)d_in[3];  // 20480
    // d_in[4] res_path: structure is deterministic, traversed directly

    float* out0 = (float*)d_out;            // 1024x80
    float* out1 = out0 + (size_t)B_ * C_;   // 1024x255

    char* ws = (char*)d_ws;
    float* p_ws    = (float*)ws;                          // 1 MB  (1024x256 fp32)
    short* xb      = (short*)(ws + (1u << 20));           // 1 MB  (1024x512 bf16)
    short* wb      = (short*)(ws + (2u << 20));           // 20 MB (20480x512 bf16)
    float* partial = (float*)(ws + (22u << 20));          // 21 MB (64x1024x80 fp32)

    convert_kernel<<<2048, 256, 0, stream>>>(lW, x, wb, xb);
    node_kernel<<<B_ / 4, 256, 0, stream>>>(x, ne, out1, p_ws);
    gemm_kernel<<<512, 256, 0, stream>>>(xb, wb, p_ws, lb, partial);
    reduce_kernel<<<(B_ * C_) / 256, 256, 0, stream>>>(partial, out0);
}

// Round 2
// 143.147 us; speedup vs baseline: 1.0815x; 1.0815x over previous
//
#include <hip/hip_runtime.h>
#include <stdint.h>

// Problem constants
#define B_  1024
#define D_  512
#define K_  255
#define L_  256
#define C_  80

typedef __attribute__((ext_vector_type(8))) short bf16x8;
typedef __attribute__((ext_vector_type(4))) float f32x4;
typedef __attribute__((ext_vector_type(8))) short short8;

// async global->LDS, 16B per lane; dst must be wave-uniform base + lane*16.
#define GLD(gsrc, ldst) \
  __builtin_amdgcn_global_load_lds((const __attribute__((address_space(1))) void*)(gsrc), \
                                   (__attribute__((address_space(3))) void*)(ldst), 16, 0, 0)

__device__ __forceinline__ short cvt_bf16(float f) {
    unsigned u = __float_as_uint(f);
    u += 0x7FFFu + ((u >> 16) & 1u);
    return (short)(u >> 16);
}

// ---------------------------------------------------------------------------
// Kernel 1: convert W (20480x512) + x (1024x512) fp32->bf16, AND normalize
// ne rows -> bf16 neb (256 rows; row 255 zeroed).
// blocks [0,2048): grid-stride W/x convert. blocks [2048,2304): ne rows.
// ---------------------------------------------------------------------------
__global__ __launch_bounds__(256) void convert_kernel(const float* __restrict__ w,
                                                      const float* __restrict__ x,
                                                      const float* __restrict__ ne,
                                                      short* __restrict__ wb,
                                                      short* __restrict__ xb,
                                                      short* __restrict__ neb) {
    __shared__ float red[256];
    const int tid = threadIdx.x;
    if (blockIdx.x < 2048) {
        size_t i0 = (size_t)blockIdx.x * 256 + tid;
        const size_t stride = 2048u * 256u;
        for (size_t v = i0; v < 1310720u; v += stride) {
            float4 a = ((const float4*)w)[v * 2];
            float4 b = ((const float4*)w)[v * 2 + 1];
            short8 o;
            o[0] = cvt_bf16(a.x); o[1] = cvt_bf16(a.y); o[2] = cvt_bf16(a.z); o[3] = cvt_bf16(a.w);
            o[4] = cvt_bf16(b.x); o[5] = cvt_bf16(b.y); o[6] = cvt_bf16(b.z); o[7] = cvt_bf16(b.w);
            ((short8*)wb)[v] = o;
        }
        for (size_t v = i0; v < 65536u; v += stride) {
            float4 a = ((const float4*)x)[v * 2];
            float4 b = ((const float4*)x)[v * 2 + 1];
            short8 o;
            o[0] = cvt_bf16(a.x); o[1] = cvt_bf16(a.y); o[2] = cvt_bf16(a.z); o[3] = cvt_bf16(a.w);
            o[4] = cvt_bf16(b.x); o[5] = cvt_bf16(b.y); o[6] = cvt_bf16(b.z); o[7] = cvt_bf16(b.w);
            ((short8*)xb)[v] = o;
        }
    } else {
        const int row = blockIdx.x - 2048;  // 0..255
        if (row == 255) {
            ((unsigned*)(neb + 255 * 512))[tid] = 0u;  // pad row = zeros
            return;
        }
        const float2* nr = (const float2*)(ne + (size_t)row * 512);
        float2 a = nr[tid];  // elems 2t, 2t+1 (coalesced)
        red[tid] = a.x * a.x + a.y * a.y;
        __syncthreads();
        #pragma unroll
        for (int s = 128; s > 0; s >>= 1) {
            if (tid < s) red[tid] += red[tid + s];
            __syncthreads();
        }
        float inv = rsqrtf(red[0]);
        unsigned lo = (unsigned short)cvt_bf16(a.x * inv);
        unsigned hi = (unsigned short)cvt_bf16(a.y * inv);
        ((unsigned*)(neb + (size_t)row * 512))[tid] = lo | (hi << 16);
    }
}

// ---------------------------------------------------------------------------
// Kernel 2: sim GEMM: out1[b,k] = sigmoid(xb[b,:]·neb[k,:]). M=1024,N=255,K=512.
// Block tile 64x64, grid = 16 mt x 4 nt = 64 blocks, 4 waves.
// ---------------------------------------------------------------------------
__global__ __launch_bounds__(256) void simgemm_kernel(const short* __restrict__ xb,
                                                      const short* __restrict__ neb,
                                                      float* __restrict__ out1) {
    __shared__ __align__(16) short Ald[512 * 8];  // 64x64 bf16 = 8 KB
    __shared__ __align__(16) short Bld[512 * 8];
    const int tid = threadIdx.x;
    const int lane = tid & 63, wave = tid >> 6;
    const int q = lane >> 4, r = lane & 15;
    const int mt = blockIdx.x >> 2;  // 0..15
    const int nt = blockIdx.x & 3;   // 0..3

    f32x4 acc[4];
    #pragma unroll
    for (int nf = 0; nf < 4; ++nf) acc[nf] = (f32x4){0.f, 0.f, 0.f, 0.f};

    const bf16x8* Av = (const bf16x8*)Ald;
    const bf16x8* Bv = (const bf16x8*)Bld;

    for (int kb = 0; kb < 8; ++kb) {
        __syncthreads();
        #pragma unroll
        for (int j = 0; j < 2; ++j) {
            int ph = j * 256 + tid, rr = ph >> 3, g = (ph & 7) ^ (rr & 7);
            GLD(xb + ((size_t)(mt * 64 + rr) * D_ + kb * 64 + g * 8), Ald + ph * 8);
        }
        #pragma unroll
        for (int j = 0; j < 2; ++j) {
            int ph = j * 256 + tid, cc = ph >> 3, g = (ph & 7) ^ (cc & 7);
            GLD(neb + ((size_t)(nt * 64 + cc) * D_ + kb * 64 + g * 8), Bld + ph * 8);
        }
        __syncthreads();
        #pragma unroll
        for (int ks = 0; ks < 2; ++ks) {
            const int g = ks * 4 + q;
            int rl = wave * 16 + r;
            bf16x8 af = Av[rl * 8 + (g ^ (rl & 7))];
            #pragma unroll
            for (int nf = 0; nf < 4; ++nf) {
                int cl = nf * 16 + r;
                bf16x8 bfr = Bv[cl * 8 + (g ^ (cl & 7))];
                acc[nf] = __builtin_amdgcn_mfma_f32_16x16x32_bf16(af, bfr, acc[nf], 0, 0, 0);
            }
        }
    }
    #pragma unroll
    for (int nf = 0; nf < 4; ++nf) {
        int gcol = nt * 64 + nf * 16 + r;
        if (gcol < K_) {
            #pragma unroll
            for (int i = 0; i < 4; ++i) {
                int grow = mt * 64 + wave * 16 + q * 4 + i;
                out1[(size_t)grow * K_ + gcol] = 1.f / (1.f + __expf(-acc[nf][i]));
            }
        }
    }
}

// ---------------------------------------------------------------------------
// Kernel 3: leaf probabilities from out1 (sigmoids). Block = batch row.
// ---------------------------------------------------------------------------
__global__ __launch_bounds__(256) void leafprob_kernel(const float* __restrict__ out1,
                                                       float* __restrict__ p_ws) {
    __shared__ float ss[K_];
    const int b = blockIdx.x, t = threadIdx.x;
    if (t < K_) ss[t] = out1[(size_t)b * K_ + t];
    __syncthreads();
    float prob = 1.f;
    int node = 0;
    #pragma unroll
    for (int d = 0; d < 8; ++d) {
        int bit = (t >> (7 - d)) & 1;
        float s = ss[node];
        prob *= bit ? (1.f - s) : s;
        node = 2 * node + 1 + bit;
    }
    p_ws[(size_t)b * L_ + t] = prob;
}

// ---------------------------------------------------------------------------
// Kernel 4: main GEMM. Block tile 128 rows x 160 cols (= 2 leaves), BK=64.
// Grid = mt(8) x lp(128) = 1024 blocks; blockIdx = mt*128+lp so XCD = lp%8
// (all 8 m-tiles sharing a B tile on one XCD; 2.5 MB/XCD B footprint).
// Wave tile 32 rows x 160 cols: 2 m-frags x 10 n-frags, 40 MFMA per barrier.
// Epilogue folds both leaves: out = p0*(dec+b0) + p1*(dec'+b1) -> partial[lp].
// ---------------------------------------------------------------------------
__global__ __launch_bounds__(256, 4) void gemm_kernel(const short* __restrict__ xb,
                                                      const short* __restrict__ wb,
                                                      const float* __restrict__ p,
                                                      const float* __restrict__ lb,
                                                      float* __restrict__ partial) {
    __shared__ __align__(16) short Ald[1024 * 8];  // 128x64 bf16 = 16 KB
    __shared__ __align__(16) short Bld[1280 * 8];  // 160x64 bf16 = 20 KB
    __shared__ float p_ld[128][2];
    __shared__ float b_ld[160];

    const int tid = threadIdx.x;
    const int lane = tid & 63, wave = tid >> 6;
    const int q = lane >> 4, r = lane & 15;
    const int wrow = wave * 32;
    const int lp = blockIdx.x & 127;
    const int mt = blockIdx.x >> 7;

    if (tid < 128) {
        p_ld[tid][0] = p[(size_t)(mt * 128 + tid) * L_ + 2 * lp];
        p_ld[tid][1] = p[(size_t)(mt * 128 + tid) * L_ + 2 * lp + 1];
    }
    if (tid < 160) b_ld[tid] = lb[lp * 160 + tid];

    f32x4 dec[2][10];
    #pragma unroll
    for (int mf = 0; mf < 2; ++mf)
        #pragma unroll
        for (int nf = 0; nf < 10; ++nf)
            dec[mf][nf] = (f32x4){0.f, 0.f, 0.f, 0.f};

    const bf16x8* Av = (const bf16x8*)Ald;
    const bf16x8* Bv = (const bf16x8*)Bld;

    for (int kb = 0; kb < 8; ++kb) {
        __syncthreads();
        #pragma unroll
        for (int j = 0; j < 4; ++j) {
            int ph = j * 256 + tid, rr = ph >> 3, g = (ph & 7) ^ (rr & 7);
            GLD(xb + ((size_t)(mt * 128 + rr) * D_ + kb * 64 + g * 8), Ald + ph * 8);
        }
        #pragma unroll
        for (int j = 0; j < 5; ++j) {
            int ph = j * 256 + tid, cc = ph >> 3, g = (ph & 7) ^ (cc & 7);
            GLD(wb + ((size_t)(lp * 160 + cc) * D_ + kb * 64 + g * 8), Bld + ph * 8);
        }
        __syncthreads();
        #pragma unroll
        for (int ks = 0; ks < 2; ++ks) {
            const int g = ks * 4 + q;
            bf16x8 af[2];
            #pragma unroll
            for (int mf = 0; mf < 2; ++mf) {
                int rl = wrow + mf * 16 + r;
                af[mf] = Av[rl * 8 + (g ^ (rl & 7))];
            }
            #pragma unroll
            for (int half = 0; half < 2; ++half) {  // halves limit live B-frags (VGPR cap 128)
                bf16x8 bfr[5];
                #pragma unroll
                for (int nf = 0; nf < 5; ++nf) {
                    int cl = half * 80 + nf * 16 + r;
                    bfr[nf] = Bv[cl * 8 + (g ^ (cl & 7))];
                }
                #pragma unroll
                for (int mf = 0; mf < 2; ++mf)
                    #pragma unroll
                    for (int nf = 0; nf < 5; ++nf)
                        dec[mf][half * 5 + nf] = __builtin_amdgcn_mfma_f32_16x16x32_bf16(
                            af[mf], bfr[nf], dec[mf][half * 5 + nf], 0, 0, 0);
            }
        }
    }

    // epilogue: fold the two leaves, write partial[lp][row][c]
    const size_t rbase = (size_t)lp * B_ + mt * 128;
    #pragma unroll
    for (int mf = 0; mf < 2; ++mf) {
        #pragma unroll
        for (int nf = 0; nf < 5; ++nf) {
            int c = nf * 16 + r;
            float b0 = b_ld[c], b1 = b_ld[80 + c];
            #pragma unroll
            for (int i = 0; i < 4; ++i) {
                int row = wrow + mf * 16 + q * 4 + i;
                float v = p_ld[row][0] * (dec[mf][nf][i] + b0)
                        + p_ld[row][1] * (dec[mf][nf + 5][i] + b1);
                partial[(rbase + row) * C_ + c] = v;
            }
        }
    }
}

// ---------------------------------------------------------------------------
// Kernel 5: reduce 128 lp partials -> out0 (1024x80)
// ---------------------------------------------------------------------------
__global__ __launch_bounds__(256) void reduce_kernel(const float* __restrict__ partial,
                                                     float* __restrict__ out0) {
    int idx = blockIdx.x * 256 + threadIdx.x;  // < 81920
    float s = 0.f;
    #pragma unroll 8
    for (int j = 0; j < 128; ++j)
        s += partial[(size_t)j * (B_ * C_) + idx];
    out0[idx] = s;
}

// ---------------------------------------------------------------------------
extern "C" void kernel_launch(void* const* d_in, const int* in_sizes, int n_in,
                              void* d_out, int out_size, void* d_ws, size_t ws_size,
                              hipStream_t stream) {
    const float* x  = (const float*)d_in[0];  // 1024x512
    const float* ne = (const float*)d_in[1];  // 255x512
    const float* lW = (const float*)d_in[2];  // 20480x512
    const float* lb = (const float*)d_in[3];  // 20480
    // d_in[4] res_path: deterministic structure, traversed directly

    float* out0 = (float*)d_out;            // 1024x80
    float* out1 = out0 + (size_t)B_ * C_;   // 1024x255

    char* ws = (char*)d_ws;
    short* xb      = (short*)ws;                            // 1 MB
    short* neb     = (short*)(ws + (1u << 20));             // 256 KB (256x512 bf16)
    float* p_ws    = (float*)(ws + (1u << 20) + (1u << 18)); // 1 MB
    short* wb      = (short*)(ws + (9u << 18));             // 2.25 MB offset, 20 MB
    float* partial = (float*)(ws + (24u << 20));            // 40 MB (128x1024x80 fp32); total 64 MiB

    convert_kernel<<<2304, 256, 0, stream>>>(lW, x, ne, wb, xb, neb);
    simgemm_kernel<<<64, 256, 0, stream>>>(xb, neb, out1);
    leafprob_kernel<<<B_, 256, 0, stream>>>(out1, p_ws);
    gemm_kernel<<<1024, 256, 0, stream>>>(xb, wb, p_ws, lb, partial);
    reduce_kernel<<<(B_ * C_) / 256, 256, 0, stream>>>(partial, out0);
}